// Round 5
// baseline (578.867 us; speedup 1.0000x reference)
//
#include <hip/hip_runtime.h>

#define D 256
#define H 256
#define O 24
#define R 128         // rows per block
#define T 256         // threads per block (4 waves); each wave owns 32 rows
#define LDSW 260      // fp32 LDS row stride: 16B-aligned, 2-way-max bank aliasing
#define LGW 25        // logits LDS stride

typedef __attribute__((ext_vector_type(4))) float f32x4;
typedef __attribute__((ext_vector_type(8))) unsigned short us8;
typedef __attribute__((ext_vector_type(8))) __bf16 bf16x8;
typedef __attribute__((ext_vector_type(4))) unsigned int u32x4;

// d_ws layout (ushort units), piece-interleaved so the per-layer fragment
// stream is a single sequential sweep through memory:
//   tile(kb,nb) = ((kb*NB + nb)*3 + piece)*512 + lane*8 + j   (3 KB per (kb,nb))
//   wf1 @ 0 (384 KB) | wf2 @ 196608 (384 KB) | wf3 @ 393216 (48 KB)
#define WF2_OFF 196608
#define WF3_OFF 393216

// Exact 3-piece bf16 split (RNE): v == h + m + l to ~2^-27 relative.
__device__ __forceinline__ void split3(float v, unsigned short& h, unsigned short& m,
                                       unsigned short& l) {
    unsigned u = __float_as_uint(v);
    unsigned hb = (u + 0x7fffu + ((u >> 16) & 1u)) >> 16;
    float r = v - __uint_as_float(hb << 16);
    unsigned ur = __float_as_uint(r);
    unsigned mb = (ur + 0x7fffu + ((ur >> 16) & 1u)) >> 16;
    float r2 = r - __uint_as_float(mb << 16);
    unsigned ul = __float_as_uint(r2);
    unsigned lb = (ul + 0x7fffu + ((ul >> 16) & 1u)) >> 16;
    h = (unsigned short)hb; m = (unsigned short)mb; l = (unsigned short)lb;
}

__device__ __forceinline__ f32x4 mfma16(us8 a, us8 b, f32x4 c) {
    return __builtin_amdgcn_mfma_f32_16x16x32_bf16(
        __builtin_bit_cast(bf16x8, a), __builtin_bit_cast(bf16x8, b), c, 0, 0, 0);
}

// ---- pre-split W1/W2/W3 into B-fragment-linear bf16 pieces ----
__global__ void split_w(const float* __restrict__ W1, const float* __restrict__ W2,
                        const float* __restrict__ W3, unsigned short* __restrict__ wf)
{
    const int bid = blockIdx.x;        // 0..271
    const int lane = threadIdx.x;      // 0..63
    const int q = lane >> 4, ln = lane & 15;
    const float* src; unsigned short* dst; int nbcnt, ld, ncols, kb, nb;
    if (bid < 256) {
        int mat = bid >> 7; kb = (bid >> 4) & 7; nb = bid & 15;
        src = mat ? W2 : W1; dst = wf + (mat ? WF2_OFF : 0);
        nbcnt = 16; ld = H; ncols = H;
    } else {
        int b = bid - 256; kb = b >> 1; nb = b & 1;
        src = W3; dst = wf + WF3_OFF; nbcnt = 2; ld = O; ncols = O;
    }
    const int n = nb * 16 + ln;
    #pragma unroll
    for (int j = 0; j < 8; ++j) {
        const int k = kb * 32 + q * 8 + j;
        float v = (n < ncols) ? src[(size_t)k * ld + n] : 0.f;
        unsigned short h, m, l; split3(v, h, m, l);
        size_t base = ((size_t)(kb * nbcnt + nb) * 3) * 512 + (size_t)lane * 8 + j;
        dst[base] = h; dst[base + 512] = m; dst[base + 1024] = l;
    }
}

// One MFMA layer for a wave's 32-row strip (2 row-tiles of 16).
// Reads fp32 activations from LDS, splits to 3 bf16 A-frags per K-block,
// 6 passes vs pre-split B-frags shared across both row-tiles.
// Wave-private rows -> no barriers.
template <int NB>
__device__ __forceinline__ void mfma_layer(const float* __restrict__ hrow, // &hbuf[m0][0]
                                           const u32x4* __restrict__ wf,
                                           const float* __restrict__ bias, int ncols,
                                           int lane, f32x4 acc[2][NB])
{
    const int ln = lane & 15, q = lane >> 4;
    #pragma unroll
    for (int nb = 0; nb < NB; ++nb) {
        const int c = nb * 16 + ln;
        const float bv = (c < ncols) ? bias[c] : 0.f;
        #pragma unroll
        for (int rt = 0; rt < 2; ++rt) acc[rt][nb] = (f32x4){bv, bv, bv, bv};
    }
    #pragma unroll 2
    for (int kb = 0; kb < 8; ++kb) {
        us8 ah[2], am[2], al[2];
        #pragma unroll
        for (int rt = 0; rt < 2; ++rt) {
            const float* ap = hrow + (size_t)(rt * 16 + ln) * LDSW + kb * 32 + q * 8;
            f32x4 x0 = *(const f32x4*)ap;          // ds_read_b128
            f32x4 x1 = *(const f32x4*)(ap + 4);
            #pragma unroll
            for (int j = 0; j < 8; ++j) {
                const float v = (j < 4) ? x0[j] : x1[j - 4];
                unsigned short h, m, l; split3(v, h, m, l);
                ah[rt][j] = h; am[rt][j] = m; al[rt][j] = l;
            }
        }
        const u32x4* wp = wf + (size_t)kb * NB * 192 + lane;
        #pragma unroll
        for (int nb = 0; nb < NB; ++nb) {
            us8 bh = __builtin_bit_cast(us8, wp[(size_t)nb * 192]);
            us8 bm = __builtin_bit_cast(us8, wp[(size_t)nb * 192 + 64]);
            us8 bl = __builtin_bit_cast(us8, wp[(size_t)nb * 192 + 128]);
            #pragma unroll
            for (int rt = 0; rt < 2; ++rt) {
                acc[rt][nb] = mfma16(ah[rt], bh, acc[rt][nb]);
                acc[rt][nb] = mfma16(am[rt], bh, acc[rt][nb]);
                acc[rt][nb] = mfma16(al[rt], bh, acc[rt][nb]);
                acc[rt][nb] = mfma16(ah[rt], bm, acc[rt][nb]);
                acc[rt][nb] = mfma16(am[rt], bm, acc[rt][nb]);
                acc[rt][nb] = mfma16(ah[rt], bl, acc[rt][nb]);
            }
        }
    }
}

__global__ __launch_bounds__(T, 1) void fused_mlp_topk(
    const float* __restrict__ x,
    const float* __restrict__ b1, const float* __restrict__ b2, const float* __restrict__ b3,
    const u32x4* __restrict__ wfrag, float* __restrict__ out)
{
    __shared__ float hbuf[R][LDSW];          // x -> h1 -> h2, in place (133120 B)
    __shared__ float logitsB[R][LGW];        // 12800 B
    __shared__ unsigned selmask[R];          // 512 B

    const int t = threadIdx.x;
    const int lane = t & 63, w = t >> 6;
    const int ln = lane & 15, q = lane >> 4;
    const long row0 = (long)blockIdx.x * R;
    const int m0 = w * 32;                   // wave-private 32-row strip

    // ---- stage this wave's 32 rows (coalesced f32x4; no barrier needed) ----
    #pragma unroll 4
    for (int r = 0; r < 32; ++r) {
        const int row = m0 + r;
        *(f32x4*)&hbuf[row][lane * 4] = *(const f32x4*)(x + (row0 + row) * D + lane * 4);
    }

    f32x4 acc[2][16];

    // ---- Layer 1 (in place; wave reads/writes only its own rows) ----
    mfma_layer<16>(&hbuf[m0][0], wfrag, b1, H, lane, acc);
    #pragma unroll
    for (int rt = 0; rt < 2; ++rt)
        #pragma unroll
        for (int nb = 0; nb < 16; ++nb)
            #pragma unroll
            for (int rg = 0; rg < 4; ++rg)
                hbuf[m0 + rt * 16 + q * 4 + rg][nb * 16 + ln] = fmaxf(acc[rt][nb][rg], 0.f);

    // ---- Layer 2 ----
    mfma_layer<16>(&hbuf[m0][0], wfrag + WF2_OFF / 8, b2, H, lane, acc);
    #pragma unroll
    for (int rt = 0; rt < 2; ++rt)
        #pragma unroll
        for (int nb = 0; nb < 16; ++nb)
            #pragma unroll
            for (int rg = 0; rg < 4; ++rg)
                hbuf[m0 + rt * 16 + q * 4 + rg][nb * 16 + ln] = fmaxf(acc[rt][nb][rg], 0.f);

    // ---- Layer 3 (2 col-tiles, cols 24..31 zero-padded in wf3) ----
    f32x4 acc3[2][2];
    mfma_layer<2>(&hbuf[m0][0], wfrag + WF3_OFF / 8, b3, O, lane, acc3);
    #pragma unroll
    for (int rt = 0; rt < 2; ++rt)
        #pragma unroll
        for (int nb = 0; nb < 2; ++nb)
            #pragma unroll
            for (int rg = 0; rg < 4; ++rg) {
                const int c = nb * 16 + ln;
                if (c < O) logitsB[m0 + rt * 16 + q * 4 + rg][c] = acc3[rt][nb][rg];
            }
    __syncthreads();

    // ---- top-6 of the 22 selected columns (cols != 0,12), one thread per row ----
    if (t < R) {
        float v[22];
        #pragma unroll
        for (int i = 0; i < 22; ++i) {
            const int j = (i < 11) ? (i + 1) : (i + 2);
            v[i] = logitsB[t][j];
        }
        unsigned taken = 0u;
        unsigned cm = 1u | (1u << 12);
        for (int kk = 0; kk < 6; ++kk) {
            float best = -3.4e38f; int bi = 0;
            #pragma unroll
            for (int i = 0; i < 22; ++i) {
                if (!((taken >> i) & 1u) && v[i] > best) { best = v[i]; bi = i; }
            }
            taken |= 1u << bi;
            cm |= 1u << ((bi < 11) ? (bi + 1) : (bi + 2));
        }
        selmask[t] = cm;
    }
    __syncthreads();

    // ---- write mask (coalesced) ----
    #pragma unroll
    for (int i = 0; i < (R * O) / T; ++i) {
        const int idx = i * T + t;
        const int r = idx / O;
        const int j = idx - r * O;
        out[row0 * O + idx] = ((selmask[r] >> j) & 1u) ? 1.0f : 0.0f;
    }
}

extern "C" void kernel_launch(void* const* d_in, const int* in_sizes, int n_in,
                              void* d_out, int out_size, void* d_ws, size_t ws_size,
                              hipStream_t stream) {
    const float* x  = (const float*)d_in[0];
    const float* W1 = (const float*)d_in[1];
    const float* b1 = (const float*)d_in[2];
    const float* W2 = (const float*)d_in[3];
    const float* b2 = (const float*)d_in[4];
    const float* W3 = (const float*)d_in[5];
    const float* b3 = (const float*)d_in[6];
    float* out = (float*)d_out;

    unsigned short* wf = (unsigned short*)d_ws;
    hipLaunchKernelGGL(split_w, dim3(272), dim3(64), 0, stream, W1, W2, W3, wf);

    const int B = in_sizes[0] / D;   // 131072
    const int nblk = B / R;          // 1024
    hipLaunchKernelGGL(fused_mlp_topk, dim3(nblk), dim3(T), 0, stream,
                       x, b1, b2, b3, (const u32x4*)d_ws, out);
}

// Round 6
// 405.132 us; speedup vs baseline: 1.4288x; 1.4288x over previous
//
#include <hip/hip_runtime.h>

#define D 256
#define H 256
#define O 24
#define R 64          // rows per block
#define T 512         // threads per block: 8 waves; wave = 64 rows x 32 cols
#define PW 264        // bf16 row stride for piece buffers (16B pad -> 2-way banks, free)
#define PS (R * PW)   // piece stride in ushort

typedef __attribute__((ext_vector_type(4))) float f32x4;
typedef __attribute__((ext_vector_type(4))) unsigned short us4;
typedef __attribute__((ext_vector_type(8))) unsigned short us8;
typedef __attribute__((ext_vector_type(8))) __bf16 bf16x8;
typedef __attribute__((ext_vector_type(4))) unsigned int u32x4;

// d_ws layout (ushort units): tile(kb,nb) base = ((kb*NB+nb)*3)*512, pieces +0/+512/+1024
//   wf1 @ 0 (384 KB) | wf2 @ 196608 (384 KB) | wf3 @ 393216 (48 KB)
#define WF2_OFF 196608
#define WF3_OFF 393216

// Exact 3-piece bf16 split (RNE): v == h + m + l to ~2^-27 relative.
__device__ __forceinline__ void split3(float v, unsigned short& h, unsigned short& m,
                                       unsigned short& l) {
    unsigned u = __float_as_uint(v);
    unsigned hb = (u + 0x7fffu + ((u >> 16) & 1u)) >> 16;
    float r = v - __uint_as_float(hb << 16);
    unsigned ur = __float_as_uint(r);
    unsigned mb = (ur + 0x7fffu + ((ur >> 16) & 1u)) >> 16;
    float r2 = r - __uint_as_float(mb << 16);
    unsigned ul = __float_as_uint(r2);
    unsigned lb = (ul + 0x7fffu + ((ul >> 16) & 1u)) >> 16;
    h = (unsigned short)hb; m = (unsigned short)mb; l = (unsigned short)lb;
}

__device__ __forceinline__ f32x4 mfma16(us8 a, us8 b, f32x4 c) {
    return __builtin_amdgcn_mfma_f32_16x16x32_bf16(
        __builtin_bit_cast(bf16x8, a), __builtin_bit_cast(bf16x8, b), c, 0, 0, 0);
}

// 6-pass fp32-accurate product: ah*bh + am*bh + al*bh + ah*bm + am*bm + ah*bl
__device__ __forceinline__ f32x4 mfma6(const us8* a, const us8* b, f32x4 c) {
    c = mfma16(a[0], b[0], c);
    c = mfma16(a[1], b[0], c);
    c = mfma16(a[2], b[0], c);
    c = mfma16(a[0], b[1], c);
    c = mfma16(a[1], b[1], c);
    c = mfma16(a[0], b[2], c);
    return c;
}

// ---- pre-split W1/W2/W3 into B-fragment-linear bf16 pieces (same as R4/R5) ----
__global__ void split_w(const float* __restrict__ W1, const float* __restrict__ W2,
                        const float* __restrict__ W3, unsigned short* __restrict__ wf)
{
    const int bid = blockIdx.x;        // 0..271
    const int lane = threadIdx.x;      // 0..63
    const int q = lane >> 4, ln = lane & 15;
    const float* src; unsigned short* dst; int nbcnt, ld, ncols, kb, nb;
    if (bid < 256) {
        int mat = bid >> 7; kb = (bid >> 4) & 7; nb = bid & 15;
        src = mat ? W2 : W1; dst = wf + (mat ? WF2_OFF : 0);
        nbcnt = 16; ld = H; ncols = H;
    } else {
        int b = bid - 256; kb = b >> 1; nb = b & 1;
        src = W3; dst = wf + WF3_OFF; nbcnt = 2; ld = O; ncols = O;
    }
    const int n = nb * 16 + ln;
    #pragma unroll
    for (int j = 0; j < 8; ++j) {
        const int k = kb * 32 + q * 8 + j;
        float v = (n < ncols) ? src[(size_t)k * ld + n] : 0.f;
        unsigned short h, m, l; split3(v, h, m, l);
        size_t base = ((size_t)(kb * nbcnt + nb) * 3) * 512 + (size_t)lane * 8 + j;
        dst[base] = h; dst[base + 512] = m; dst[base + 1024] = l;
    }
}

// One wave computes 64 rows x 2 col-tiles from pre-split piece buffers.
// A-frags: one ds_read_b128 per (rt,piece). B-frags: one dwordx4 per (nb,piece),
// each tile read by exactly ONE wave in the block.
__device__ __forceinline__ void big_layer(const unsigned short* __restrict__ pb,
                                          const u32x4* __restrict__ wfL,
                                          const float* __restrict__ bias,
                                          int nb0, int lane, f32x4 acc[4][2])
{
    const int ln = lane & 15, q = lane >> 4;
    #pragma unroll
    for (int nb = 0; nb < 2; ++nb) {
        const float bv = bias[(nb0 + nb) * 16 + ln];
        #pragma unroll
        for (int rt = 0; rt < 4; ++rt) acc[rt][nb] = (f32x4){bv, bv, bv, bv};
    }
    #pragma unroll 2
    for (int kb = 0; kb < 8; ++kb) {
        us8 bb[2][3];
        #pragma unroll
        for (int nb = 0; nb < 2; ++nb)
            #pragma unroll
            for (int p = 0; p < 3; ++p)
                bb[nb][p] = __builtin_bit_cast(us8,
                    wfL[((size_t)(kb * 16 + nb0 + nb) * 3 + p) * 64 + lane]);
        us8 aa[4][3];
        #pragma unroll
        for (int rt = 0; rt < 4; ++rt)
            #pragma unroll
            for (int p = 0; p < 3; ++p)
                aa[rt][p] = *(const us8*)(pb + (size_t)p * PS +
                                          (size_t)(rt * 16 + ln) * PW + kb * 32 + q * 8);
        #pragma unroll
        for (int rt = 0; rt < 4; ++rt)
            #pragma unroll
            for (int nb = 0; nb < 2; ++nb)
                acc[rt][nb] = mfma6(aa[rt], bb[nb], acc[rt][nb]);
    }
}

__global__ __launch_bounds__(T) void fused_mlp_topk(
    const float* __restrict__ x,
    const float* __restrict__ b1, const float* __restrict__ b2, const float* __restrict__ b3,
    const u32x4* __restrict__ wfrag, float* __restrict__ out)
{
    __shared__ __align__(16) unsigned short pbuf[3][R][PW];   // 101376 B, x->h1->h2
    __shared__ float logitsB[R][25];                          // 6400 B
    __shared__ unsigned selmask[R];                           // 256 B

    const int t = threadIdx.x;
    const int lane = t & 63, w = t >> 6;     // wave id 0..7
    const int ln = lane & 15, q = lane >> 4;
    const long row0 = (long)blockIdx.x * R;
    unsigned short* pb = &pbuf[0][0][0];

    // ---- stage + split x once (coalesced f32x4 reads, b64 piece writes) ----
    #pragma unroll
    for (int it = 0; it < 8; ++it) {
        const int idx = it * T + t;          // 0..4095 quads
        const int row = idx >> 6;
        const int c4 = (idx & 63) * 4;
        f32x4 v = *(const f32x4*)(x + (row0 + row) * D + c4);
        us4 ph, pm, pl;
        #pragma unroll
        for (int j = 0; j < 4; ++j) {
            unsigned short h, m, l; split3(v[j], h, m, l);
            ph[j] = h; pm[j] = m; pl[j] = l;
        }
        *(us4*)(pb + 0 * PS + (size_t)row * PW + c4) = ph;
        *(us4*)(pb + 1 * PS + (size_t)row * PW + c4) = pm;
        *(us4*)(pb + 2 * PS + (size_t)row * PW + c4) = pl;
    }
    __syncthreads();

    const int nb0 = 2 * w;   // this wave's two col-tiles
    f32x4 acc[4][2];

    // ---- Layer 1 ----
    big_layer(pb, wfrag, b1, nb0, lane, acc);
    __syncthreads();         // all reads of x-pieces done
    #pragma unroll
    for (int rt = 0; rt < 4; ++rt)
        #pragma unroll
        for (int nb = 0; nb < 2; ++nb)
            #pragma unroll
            for (int rg = 0; rg < 4; ++rg) {
                unsigned short h, m, l;
                split3(fmaxf(acc[rt][nb][rg], 0.f), h, m, l);
                const size_t off = (size_t)(rt * 16 + q * 4 + rg) * PW + (nb0 + nb) * 16 + ln;
                pb[off] = h; pb[PS + off] = m; pb[2 * PS + off] = l;
            }
    __syncthreads();

    // ---- Layer 2 ----
    big_layer(pb, wfrag + WF2_OFF / 8, b2, nb0, lane, acc);
    __syncthreads();
    #pragma unroll
    for (int rt = 0; rt < 4; ++rt)
        #pragma unroll
        for (int nb = 0; nb < 2; ++nb)
            #pragma unroll
            for (int rg = 0; rg < 4; ++rg) {
                unsigned short h, m, l;
                split3(fmaxf(acc[rt][nb][rg], 0.f), h, m, l);
                const size_t off = (size_t)(rt * 16 + q * 4 + rg) * PW + (nb0 + nb) * 16 + ln;
                pb[off] = h; pb[PS + off] = m; pb[2 * PS + off] = l;
            }
    __syncthreads();

    // ---- Layer 3: wave w -> row-tile (w&3), col-tile (w>>2); cols 24..31 zero-padded ----
    {
        const int rt3 = w & 3, nb3 = w >> 2;
        const int c = nb3 * 16 + ln;
        const float bv = (c < O) ? b3[c] : 0.f;
        f32x4 a3 = (f32x4){bv, bv, bv, bv};
        const u32x4* wf3 = wfrag + WF3_OFF / 8;
        #pragma unroll 2
        for (int kb = 0; kb < 8; ++kb) {
            us8 bb[3], aa[3];
            #pragma unroll
            for (int p = 0; p < 3; ++p) {
                bb[p] = __builtin_bit_cast(us8, wf3[((size_t)(kb * 2 + nb3) * 3 + p) * 64 + lane]);
                aa[p] = *(const us8*)(pb + (size_t)p * PS +
                                      (size_t)(rt3 * 16 + ln) * PW + kb * 32 + q * 8);
            }
            a3 = mfma6(aa, bb, a3);
        }
        #pragma unroll
        for (int rg = 0; rg < 4; ++rg)
            if (c < O) logitsB[rt3 * 16 + q * 4 + rg][c] = a3[rg];
    }
    __syncthreads();

    // ---- top-6 of the 22 selected columns (cols != 0,12), one thread per row ----
    if (t < R) {
        float v[22];
        #pragma unroll
        for (int i = 0; i < 22; ++i) {
            const int j = (i < 11) ? (i + 1) : (i + 2);
            v[i] = logitsB[t][j];
        }
        unsigned taken = 0u;
        unsigned cm = 1u | (1u << 12);
        for (int kk = 0; kk < 6; ++kk) {
            float best = -3.4e38f; int bi = 0;
            #pragma unroll
            for (int i = 0; i < 22; ++i) {
                if (!((taken >> i) & 1u) && v[i] > best) { best = v[i]; bi = i; }
            }
            taken |= 1u << bi;
            cm |= 1u << ((bi < 11) ? (bi + 1) : (bi + 2));
        }
        selmask[t] = cm;
    }
    __syncthreads();

    // ---- write mask (coalesced) ----
    #pragma unroll
    for (int i = 0; i < (R * O) / T; ++i) {
        const int idx = i * T + t;
        const int r = idx / O;
        const int j = idx - r * O;
        out[row0 * O + idx] = ((selmask[r] >> j) & 1u) ? 1.0f : 0.0f;
    }
}

extern "C" void kernel_launch(void* const* d_in, const int* in_sizes, int n_in,
                              void* d_out, int out_size, void* d_ws, size_t ws_size,
                              hipStream_t stream) {
    const float* x  = (const float*)d_in[0];
    const float* W1 = (const float*)d_in[1];
    const float* b1 = (const float*)d_in[2];
    const float* W2 = (const float*)d_in[3];
    const float* b2 = (const float*)d_in[4];
    const float* W3 = (const float*)d_in[5];
    const float* b3 = (const float*)d_in[6];
    float* out = (float*)d_out;

    unsigned short* wf = (unsigned short*)d_ws;
    hipLaunchKernelGGL(split_w, dim3(272), dim3(64), 0, stream, W1, W2, W3, wf);

    const int B = in_sizes[0] / D;   // 131072
    const int nblk = B / R;          // 2048
    hipLaunchKernelGGL(fused_mlp_topk, dim3(nblk), dim3(T), 0, stream,
                       x, b1, b2, b3, (const u32x4*)d_ws, out);
}